// Round 5
// baseline (7113.737 us; speedup 1.0000x reference)
//
#include <hip/hip_runtime.h>

#define T_DIM 256
#define B_DIM 128
#define F_DIM 1024
#define G_DIM 4096
#define NWGS  256

typedef short bf8  __attribute__((ext_vector_type(8)));
typedef float f32x4 __attribute__((ext_vector_type(4)));
typedef unsigned long long u64;

// ---- ws layout (bytes) ----
#define OFF_FLAGS 0ull
#define OFF_WIP   4096ull
#define SZ_WPACK  (8ull*1024*1024)        // 256nt * 32kt * 64lane * 8 * 2B
#define OFF_WHP   (OFF_WIP + SZ_WPACK)
#define OFF_XPK   (OFF_WHP + SZ_WPACK)    // 256t * 32kt * 8mt * 64 * 8 * 2B = 64 MB
#define SZ_XPK    (64ull*1024*1024)
#define OFF_HP    (OFF_XPK + SZ_XPK)      // 2 * 128*1024 * 2B = 512 KB
#define WS_NEED   (OFF_HP + 2ull*131072ull*2ull)

__device__ __forceinline__ unsigned short f2bf(float v) {
  union { float f; unsigned int u; } c; c.f = v;
  unsigned int u = c.u;
  return (unsigned short)((u + 0x7fffu + ((u >> 16) & 1u)) >> 16);  // RNE
}
__device__ __forceinline__ float sigm(float x)  { return 1.f / (1.f + __expf(-x)); }
__device__ __forceinline__ float tanh_(float x) { return 1.f - 2.f / (1.f + __expf(2.f * x)); }

// ---- pack W (fp32 F x 4F) -> MFMA-B frag order bf16: frag idx (nt*32+kt)*64+lane ----
__global__ __launch_bounds__(256) void pack_w(const float* __restrict__ Wi,
                                              const float* __restrict__ Wh,
                                              unsigned short* __restrict__ wip,
                                              unsigned short* __restrict__ whp) {
  int gid = blockIdx.x * 256 + threadIdx.x;
  const float* src = (gid >= 524288) ? Wh : Wi;
  unsigned short* dst = (gid >= 524288) ? whp : wip;
  int r  = gid & 524287;
  int nt = r >> 11;
  int kt = (r >> 6) & 31;
  int l  = r & 63;
  int col = nt * 16 + (l & 15);
  int k0  = kt * 32 + ((l >> 4) << 3);
  bf8 v8;
#pragma unroll
  for (int j = 0; j < 8; ++j)
    v8[j] = (short)f2bf(src[(size_t)(k0 + j) * G_DIM + col]);
  *reinterpret_cast<bf8*>(dst + (size_t)r * 8) = v8;
}

// ---- pack all x -> A-frag order [t][kt][mt][lane][8] ----
__global__ __launch_bounds__(256) void pack_x(const float* __restrict__ x,
                                              unsigned short* __restrict__ xpk) {
  int gid = blockIdx.x * 256 + threadIdx.x;   // T*B*128 = 4,194,304
  int fb = gid & 127;
  int b  = (gid >> 7) & 127;
  int t  = gid >> 14;
  const float* s = x + ((size_t)(t * B_DIM + b)) * F_DIM + fb * 8;
  float4 v0 = *reinterpret_cast<const float4*>(s);
  float4 v1 = *reinterpret_cast<const float4*>(s + 4);
  int kt = fb >> 2, j4 = fb & 3, mt = b >> 4;
  int lane2 = (b & 15) | (j4 << 4);
  bf8 o;
  o[0] = (short)f2bf(v0.x); o[1] = (short)f2bf(v0.y);
  o[2] = (short)f2bf(v0.z); o[3] = (short)f2bf(v0.w);
  o[4] = (short)f2bf(v1.x); o[5] = (short)f2bf(v1.y);
  o[6] = (short)f2bf(v1.z); o[7] = (short)f2bf(v1.w);
  *reinterpret_cast<bf8*>(xpk + ((size_t)(((t * 32 + kt) * 8 + mt) * 64) + lane2) * 8) = o;
}

// ---- h0 fp32 -> bf16 row-major into h buffer 0 ----
__global__ __launch_bounds__(256) void pack_h(const float* __restrict__ h0,
                                              unsigned short* __restrict__ hp) {
  int i = blockIdx.x * 256 + threadIdx.x;     // 131072
  hp[i] = f2bf(h0[i]);
}

// ---- persistent scan: 256 WGs x 256 thr; wave = gate; Wh in regs (128 VGPR) ----
__global__ __launch_bounds__(256, 1) void lstm_scan(
    const unsigned short* __restrict__ xpk,
    const unsigned short* __restrict__ wip,
    const unsigned short* __restrict__ whp,
    unsigned short* __restrict__ hp,            // [2][128][1024] bf16 row-major
    const float* __restrict__ bias,
    const int*   __restrict__ term,
    const float* __restrict__ c0,
    float* __restrict__ out,
    unsigned int* __restrict__ flags) {

  __shared__ union {
    unsigned short hstage[64][64][8];           // [mt*32+kt][lane][8]  = 64 KB
    struct { float gates[4][2][16][17]; unsigned short hout[32][16]; } e;
  } sm;

  const int fg    = blockIdx.x & 63;
  const int mpair = blockIdx.x >> 6;            // 0..3 (rows mpair*32 .. +32)
  const int tid   = threadIdx.x;
  const int wv    = tid >> 6;                   // gate index 0..3 (i,f,g,o)
  const int lane  = tid & 63;
  const int col   = lane & 15;
  const int fi    = fg * 16 + col;

  // resident Wh fragments for ntile wv*64+fg  (128 VGPRs)
  bf8 wh[32];
  {
    const bf8* whb = reinterpret_cast<const bf8*>(whp) + (size_t)(wv * 64 + fg) * 2048 + lane;
#pragma unroll
    for (int kt = 0; kt < 32; ++kt) wh[kt] = whb[kt * 64];
  }
  const bf8* wib = reinterpret_cast<const bf8*>(wip) + (size_t)(wv * 64 + fg) * 2048 + lane;

  float b4[4];
#pragma unroll
  for (int g = 0; g < 4; ++g) b4[g] = bias[g * F_DIM + fi];

  float c_reg[2];
  {
    int wr0 = wv * 8 + (lane >> 4);
    c_reg[0] = c0[(size_t)(mpair * 32 + wr0)     * F_DIM + fi];
    c_reg[1] = c0[(size_t)(mpair * 32 + wr0 + 4) * F_DIM + fi];
  }

  const int srow0 = mpair * 32 + (lane & 15);   // staging row, mt=0
  const int srow1 = srow0 + 16;                 // staging row, mt=1
  const int scol  = (lane >> 4) << 3;

  float* fc = out + (size_t)T_DIM * B_DIM * F_DIM;
  float* fh = fc + (size_t)B_DIM * F_DIM;

#pragma unroll 1
  for (int t = 0; t < T_DIM; ++t) {
    // ---- wait for all WGs to have published h for this step ----
    if (t > 0) {
      if (wv == 0) {
        unsigned int tgt = (unsigned int)t;
        for (;;) {
          unsigned int f0 = __hip_atomic_load(flags + lane,       __ATOMIC_RELAXED, __HIP_MEMORY_SCOPE_AGENT);
          unsigned int f1 = __hip_atomic_load(flags + 64 + lane,  __ATOMIC_RELAXED, __HIP_MEMORY_SCOPE_AGENT);
          unsigned int f2 = __hip_atomic_load(flags + 128 + lane, __ATOMIC_RELAXED, __HIP_MEMORY_SCOPE_AGENT);
          unsigned int f3 = __hip_atomic_load(flags + 192 + lane, __ATOMIC_RELAXED, __HIP_MEMORY_SCOPE_AGENT);
          bool ok = (f0 >= tgt) & (f1 >= tgt) & (f2 >= tgt) & (f3 >= tgt);
          if (__all(ok)) break;
          __builtin_amdgcn_s_sleep(1);
        }
        asm volatile("" ::: "memory");
      }
      __syncthreads();
    }

    // ---- 1. ISSUE h loads first (critical path), buffered in registers ----
    const unsigned short* hb = hp + (size_t)(t & 1) * 131072;
    const int trm0 = term[t * B_DIM + srow0];
    const int trm1 = term[t * B_DIM + srow1];
    u64 uq0[16], uq1[16];
#pragma unroll
    for (int i = 0; i < 16; ++i) {
      int g2 = wv + 4 * i;                      // 0..63 = mt*32+kt
      int kt = g2 & 31;
      int row = (g2 >> 5) ? srow1 : srow0;
      const u64* src = reinterpret_cast<const u64*>(hb + (size_t)row * F_DIM + kt * 32 + scol);
      uq0[i] = __hip_atomic_load(const_cast<u64*>(src),     __ATOMIC_RELAXED, __HIP_MEMORY_SCOPE_AGENT);
      uq1[i] = __hip_atomic_load(const_cast<u64*>(src) + 1, __ATOMIC_RELAXED, __HIP_MEMORY_SCOPE_AGENT);
    }

    // ---- 2. x @ Wi while h is in flight ----
    f32x4 a0 = {0, 0, 0, 0}, a1 = {0, 0, 0, 0};
    const bf8* xb = reinterpret_cast<const bf8*>(xpk) + (size_t)t * 16384 + lane;
#pragma unroll
    for (int kt = 0; kt < 32; ++kt) {
      bf8 wiF = wib[kt * 64];
      bf8 x0 = xb[(kt * 8 + mpair * 2 + 0) * 64];
      bf8 x1 = xb[(kt * 8 + mpair * 2 + 1) * 64];
      a0 = __builtin_amdgcn_mfma_f32_16x16x32_bf16(x0, wiF, a0, 0, 0, 0);
      a1 = __builtin_amdgcn_mfma_f32_16x16x32_bf16(x1, wiF, a1, 0, 0, 0);
    }

    // ---- 3. write staged h to LDS (termination-masked) ----
#pragma unroll
    for (int i = 0; i < 16; ++i) {
      int g2 = wv + 4 * i;
      int msk = (g2 >> 5) ? trm1 : trm0;
      union { u64 q[2]; bf8 v; } u;
      u.q[0] = msk ? 0ull : uq0[i];
      u.q[1] = msk ? 0ull : uq1[i];
      *reinterpret_cast<bf8*>(&sm.hstage[g2][lane][0]) = u.v;
    }
    __syncthreads();

    // ---- 4. h @ Wh from LDS, weights in registers ----
#pragma unroll
    for (int kt = 0; kt < 32; ++kt) {
      bf8 h0 = *reinterpret_cast<const bf8*>(&sm.hstage[kt][lane][0]);
      bf8 h1 = *reinterpret_cast<const bf8*>(&sm.hstage[32 + kt][lane][0]);
      a0 = __builtin_amdgcn_mfma_f32_16x16x32_bf16(h0, wh[kt], a0, 0, 0, 0);
      a1 = __builtin_amdgcn_mfma_f32_16x16x32_bf16(h1, wh[kt], a1, 0, 0, 0);
    }
    __syncthreads();  // LDS reads done -> safe to alias

    // ---- 5. gate exchange ----
#pragma unroll
    for (int r = 0; r < 4; ++r) {
      sm.e.gates[wv][0][(lane >> 4) * 4 + r][col] = a0[r];
      sm.e.gates[wv][1][(lane >> 4) * 4 + r][col] = a1[r];
    }
    __syncthreads();

    // ---- 6. epilogue: each wave owns 8 rows (2 cells/lane); defer HBM stores ----
    float hn_sv[2];
#pragma unroll
    for (int c2 = 0; c2 < 2; ++c2) {
      int wr = wv * 8 + c2 * 4 + (lane >> 4);
      int mt = wr >> 4, rr = wr & 15;
      int bg = mpair * 32 + wr;
      int trm = term[t * B_DIM + bg];
      float vi = sm.e.gates[0][mt][rr][col] + b4[0];
      float vf = sm.e.gates[1][mt][rr][col] + b4[1];
      float vg = sm.e.gates[2][mt][rr][col] + b4[2];
      float vo = sm.e.gates[3][mt][rr][col] + b4[3];
      float cp = trm ? 0.f : c_reg[c2];
      float cn = sigm(vf) * cp + sigm(vi) * tanh_(vg);
      float hn = sigm(vo) * tanh_(cn);
      c_reg[c2] = cn;
      hn_sv[c2] = hn;
      sm.e.hout[wr][col] = f2bf(hn);
    }
    __syncthreads();

    // ---- 7. publish h + flag FIRST (critical path) ----
    if (wv == 0) {
      int r = lane >> 1, hh = lane & 1;
      union { u64 q[2]; bf8 v; } u;
      u.v = *reinterpret_cast<const bf8*>(&sm.e.hout[r][hh * 8]);
      unsigned short* hnext = hp + (size_t)((t + 1) & 1) * 131072;
      u64* dst = reinterpret_cast<u64*>(hnext + (size_t)(mpair * 32 + r) * F_DIM + fg * 16 + hh * 8);
      __hip_atomic_store(dst,     u.q[0], __ATOMIC_RELAXED, __HIP_MEMORY_SCOPE_AGENT);
      __hip_atomic_store(dst + 1, u.q[1], __ATOMIC_RELAXED, __HIP_MEMORY_SCOPE_AGENT);
      asm volatile("s_waitcnt vmcnt(0)" ::: "memory");
      if (lane == 0)
        __hip_atomic_store(flags + blockIdx.x, (unsigned int)(t + 1),
                           __ATOMIC_RELAXED, __HIP_MEMORY_SCOPE_AGENT);
    }

    // ---- 8. off-critical-path HBM stores ----
#pragma unroll
    for (int c2 = 0; c2 < 2; ++c2) {
      int wr = wv * 8 + c2 * 4 + (lane >> 4);
      int bg = mpair * 32 + wr;
      out[((size_t)t * B_DIM + bg) * F_DIM + fi] = hn_sv[c2];
      if (t == T_DIM - 1) {
        fc[(size_t)bg * F_DIM + fi] = c_reg[c2];
        fh[(size_t)bg * F_DIM + fi] = hn_sv[c2];
      }
    }
  }
}

extern "C" void kernel_launch(void* const* d_in, const int* in_sizes, int n_in,
                              void* d_out, int out_size, void* d_ws, size_t ws_size,
                              hipStream_t stream) {
  const float* x    = (const float*)d_in[0];
  const int*   term = (const int*)d_in[1];
  const float* c0   = (const float*)d_in[2];
  const float* h0   = (const float*)d_in[3];
  const float* Wi   = (const float*)d_in[4];
  const float* Wh   = (const float*)d_in[5];
  const float* bias = (const float*)d_in[6];
  float* out = (float*)d_out;
  char*  ws  = (char*)d_ws;

  if (ws_size < WS_NEED) return;

  unsigned int*   flags = (unsigned int*)(ws + OFF_FLAGS);
  unsigned short* wip   = (unsigned short*)(ws + OFF_WIP);
  unsigned short* whp   = (unsigned short*)(ws + OFF_WHP);
  unsigned short* xpk   = (unsigned short*)(ws + OFF_XPK);
  unsigned short* hp    = (unsigned short*)(ws + OFF_HP);

  hipMemsetAsync(flags, 0, 4096, stream);
  pack_w<<<dim3(4096),  dim3(256), 0, stream>>>(Wi, Wh, wip, whp);
  pack_x<<<dim3(16384), dim3(256), 0, stream>>>(x, xpk);
  pack_h<<<dim3(512),   dim3(256), 0, stream>>>(h0, hp);
  lstm_scan<<<dim3(NWGS), dim3(256), 0, stream>>>(xpk, wip, whp, hp, bias, term, c0, out, flags);
}

// Round 6
// 5890.314 us; speedup vs baseline: 1.2077x; 1.2077x over previous
//
#include <hip/hip_runtime.h>
#include <hip/hip_bf16.h>

#define T_DIM 256
#define B_DIM 128
#define F_DIM 1024
#define G_DIM 4096
#define NWGS  256

typedef short bf8   __attribute__((ext_vector_type(8)));
typedef float f32x4 __attribute__((ext_vector_type(4)));
typedef unsigned int u32x4 __attribute__((ext_vector_type(4)));
typedef unsigned long long u64;

// ---- ws layout (bytes) ----
// flags(4KB) + Wi-pack(8MB) + Wh-pack(8MB) + h-ring(256 slots x 256KB = 64MB)
#define OFF_FLAGS 0ull
#define OFF_WIP   4096ull
#define SZ_WPACK  (8ull*1024*1024)
#define OFF_WHP   (OFF_WIP + SZ_WPACK)
#define OFF_RING  (OFF_WHP + SZ_WPACK)
#define SZ_SLOT   (262144ull)                 // 128*1024 bf16
#define SZ_RING   (256ull * SZ_SLOT)          // 64 MB (write-once per dispatch)
#define WS_NEED   (OFF_RING + SZ_RING)        // ~80.0 MB

__device__ __forceinline__ unsigned short f2bf(float v) {
  union { float f; unsigned int u; } c; c.f = v;
  unsigned int u = c.u;
  return (unsigned short)((u + 0x7fffu + ((u >> 16) & 1u)) >> 16);  // RNE
}
__device__ __forceinline__ float sigm(float x)  { return 1.f / (1.f + __expf(-x)); }
__device__ __forceinline__ float tanh_(float x) { return 1.f - 2.f / (1.f + __expf(2.f * x)); }

// ---- pack W (fp32 F x 4F) -> MFMA-B frag order bf16: (nt*32+kt)*64+lane ----
__global__ __launch_bounds__(256) void pack_w(const float* __restrict__ Wi,
                                              const float* __restrict__ Wh,
                                              unsigned short* __restrict__ wip,
                                              unsigned short* __restrict__ whp) {
  int gid = blockIdx.x * 256 + threadIdx.x;
  const float* src = (gid >= 524288) ? Wh : Wi;
  unsigned short* dst = (gid >= 524288) ? whp : wip;
  int r  = gid & 524287;
  int nt = r >> 11;
  int kt = (r >> 6) & 31;
  int l  = r & 63;
  int col = nt * 16 + (l & 15);
  int k0  = kt * 32 + ((l >> 4) << 3);
  bf8 v8;
#pragma unroll
  for (int j = 0; j < 8; ++j)
    v8[j] = (short)f2bf(src[(size_t)(k0 + j) * G_DIM + col]);
  *reinterpret_cast<bf8*>(dst + (size_t)r * 8) = v8;
}

// ---- h0 fp32 -> bf16 row-major into ring slot 0 ----
__global__ __launch_bounds__(256) void pack_h(const float* __restrict__ h0,
                                              unsigned short* __restrict__ ring) {
  int i = blockIdx.x * 256 + threadIdx.x;     // 131072
  ring[i] = f2bf(h0[i]);
}

// ---- persistent scan: 256 WGs x 256 thr; wave = gate; Wh in regs ----
__global__ __launch_bounds__(256, 1) void lstm_scan(
    const float* __restrict__ x,                // (T,B,F) fp32
    const unsigned short* __restrict__ wip,
    const unsigned short* __restrict__ whp,
    unsigned short* __restrict__ ring,          // 256 slots, row-major bf16
    const float* __restrict__ bias,
    const int*   __restrict__ term,
    const float* __restrict__ c0,
    float* __restrict__ out,
    unsigned int* __restrict__ flags) {

  __shared__ struct {
    unsigned short hst[64][64][8];   // 64 KB  h A-frags  [mt*32+kt][lane][8]
    unsigned short xst[64][64][8];   // 64 KB  x A-frags
    float gates[4][2][16][17];       // 8.5 KB [gate][mt][row][col]
    unsigned short hout[32][16];     // 1 KB
  } sm;

  const int fg    = blockIdx.x & 63;
  const int mpair = blockIdx.x >> 6;            // 0..3 -> rows mpair*32..+32
  const int tid   = threadIdx.x;
  const int wv    = tid >> 6;                   // gate 0..3 (i,f,g,o)
  const int lane  = tid & 63;
  const int col   = lane & 15;
  const int oct   = lane >> 4;                  // k-octet 0..3
  const int fi    = fg * 16 + col;

  // resident Wh fragments for ntile wv*64+fg (128 VGPRs)
  bf8 wh[32];
  {
    const bf8* whb = reinterpret_cast<const bf8*>(whp) + (size_t)(wv * 64 + fg) * 2048 + lane;
#pragma unroll
    for (int kt = 0; kt < 32; ++kt) wh[kt] = whb[kt * 64];
  }
  const bf8* wib = reinterpret_cast<const bf8*>(wip) + (size_t)(wv * 64 + fg) * 2048 + lane;

  float b4[4];
#pragma unroll
  for (int g = 0; g < 4; ++g) b4[g] = bias[g * F_DIM + fi];

  float c_reg[2];
  {
    int wr0 = wv * 8 + oct;
    c_reg[0] = c0[(size_t)(mpair * 32 + wr0)     * F_DIM + fi];
    c_reg[1] = c0[(size_t)(mpair * 32 + wr0 + 4) * F_DIM + fi];
  }

  // staging geometry: this thread owns slots g2 = wv + 4*i (i=0..15)
  const int srow0 = mpair * 32 + col;           // global batch row when mt=0
  const int srow1 = srow0 + 16;                 // when mt=1
  const int fcol0 = oct * 8;                    // + kt*32

  float* fc = out + (size_t)T_DIM * B_DIM * F_DIM;
  float* fh = fc + (size_t)B_DIM * F_DIM;

#pragma unroll 1
  for (int t = 0; t < T_DIM; ++t) {
    // ---- A. stage x[t] -> LDS bf16 A-frags (overlaps poll wait) ----
    const float* xt = x + (size_t)t * B_DIM * F_DIM;
#pragma unroll 4
    for (int i = 0; i < 16; ++i) {
      int g2 = wv + 4 * i;
      int kt = g2 & 31;
      int grow = (g2 >> 5) ? srow1 : srow0;
      const float4* s = reinterpret_cast<const float4*>(xt + (size_t)grow * F_DIM + kt * 32 + fcol0);
      float4 v0 = s[0], v1 = s[1];
      union { __hip_bfloat162 h2[4]; u32x4 q; } cv;
      cv.h2[0] = __float22bfloat162_rn(make_float2(v0.x, v0.y));
      cv.h2[1] = __float22bfloat162_rn(make_float2(v0.z, v0.w));
      cv.h2[2] = __float22bfloat162_rn(make_float2(v1.x, v1.y));
      cv.h2[3] = __float22bfloat162_rn(make_float2(v1.z, v1.w));
      *reinterpret_cast<u32x4*>(&sm.xst[g2][lane][0]) = cv.q;
    }

    // ---- B. wait for all WGs to have published h_t (sc1 flags) ----
    if (t > 0 && wv == 0) {
      unsigned int tgt = (unsigned int)t;
      for (;;) {
        unsigned int f0 = __hip_atomic_load(flags + lane,       __ATOMIC_RELAXED, __HIP_MEMORY_SCOPE_AGENT);
        unsigned int f1 = __hip_atomic_load(flags + 64 + lane,  __ATOMIC_RELAXED, __HIP_MEMORY_SCOPE_AGENT);
        unsigned int f2 = __hip_atomic_load(flags + 128 + lane, __ATOMIC_RELAXED, __HIP_MEMORY_SCOPE_AGENT);
        unsigned int f3 = __hip_atomic_load(flags + 192 + lane, __ATOMIC_RELAXED, __HIP_MEMORY_SCOPE_AGENT);
        bool ok = (f0 >= tgt) & (f1 >= tgt) & (f2 >= tgt) & (f3 >= tgt);
        if (__all(ok)) break;
        __builtin_amdgcn_s_sleep(1);
      }
      asm volatile("" ::: "memory");
    }
    __syncthreads();   // xst staged + h_t published

    const int trm0 = term[t * B_DIM + srow0];
    const int trm1 = term[t * B_DIM + srow1];
    const unsigned short* hslot = ring + (size_t)t * 131072;

    // ---- C1. issue first 8 h loads (PLAIN cached, coalesced 16B) ----
    u32x4 hq[8];
#pragma unroll
    for (int i = 0; i < 8; ++i) {
      int g2 = wv + 4 * i;
      int kt = g2 & 31;
      int grow = (g2 >> 5) ? srow1 : srow0;
      hq[i] = *reinterpret_cast<const u32x4*>(hslot + (size_t)grow * F_DIM + kt * 32 + fcol0);
    }

    // ---- C2. x @ Wi first half (hides h latency) ----
    f32x4 a0 = {0, 0, 0, 0}, a1 = {0, 0, 0, 0};
#pragma unroll
    for (int kt = 0; kt < 16; ++kt) {
      bf8 wiF = wib[kt * 64];
      bf8 x0 = *reinterpret_cast<const bf8*>(&sm.xst[kt][lane][0]);
      bf8 x1 = *reinterpret_cast<const bf8*>(&sm.xst[32 + kt][lane][0]);
      a0 = __builtin_amdgcn_mfma_f32_16x16x32_bf16(x0, wiF, a0, 0, 0, 0);
      a1 = __builtin_amdgcn_mfma_f32_16x16x32_bf16(x1, wiF, a1, 0, 0, 0);
    }

    // ---- C3. write first 8 h frags (masked); issue last 8 loads ----
#pragma unroll
    for (int i = 0; i < 8; ++i) {
      int g2 = wv + 4 * i;
      int msk = (g2 >> 5) ? trm1 : trm0;
      u32x4 v = hq[i];
      if (msk) v = (u32x4){0, 0, 0, 0};
      *reinterpret_cast<u32x4*>(&sm.hst[g2][lane][0]) = v;
    }
#pragma unroll
    for (int i = 8; i < 16; ++i) {
      int g2 = wv + 4 * i;
      int kt = g2 & 31;
      int grow = (g2 >> 5) ? srow1 : srow0;
      hq[i - 8] = *reinterpret_cast<const u32x4*>(hslot + (size_t)grow * F_DIM + kt * 32 + fcol0);
    }

    // ---- C4. x @ Wi second half ----
#pragma unroll
    for (int kt = 16; kt < 32; ++kt) {
      bf8 wiF = wib[kt * 64];
      bf8 x0 = *reinterpret_cast<const bf8*>(&sm.xst[kt][lane][0]);
      bf8 x1 = *reinterpret_cast<const bf8*>(&sm.xst[32 + kt][lane][0]);
      a0 = __builtin_amdgcn_mfma_f32_16x16x32_bf16(x0, wiF, a0, 0, 0, 0);
      a1 = __builtin_amdgcn_mfma_f32_16x16x32_bf16(x1, wiF, a1, 0, 0, 0);
    }

    // ---- C5. write last 8 h frags ----
#pragma unroll
    for (int i = 8; i < 16; ++i) {
      int g2 = wv + 4 * i;
      int msk = (g2 >> 5) ? trm1 : trm0;
      u32x4 v = hq[i - 8];
      if (msk) v = (u32x4){0, 0, 0, 0};
      *reinterpret_cast<u32x4*>(&sm.hst[g2][lane][0]) = v;
    }
    __syncthreads();

    // ---- D. h @ Wh (weights in registers) ----
#pragma unroll
    for (int kt = 0; kt < 32; ++kt) {
      bf8 hA = *reinterpret_cast<const bf8*>(&sm.hst[kt][lane][0]);
      bf8 hB = *reinterpret_cast<const bf8*>(&sm.hst[32 + kt][lane][0]);
      a0 = __builtin_amdgcn_mfma_f32_16x16x32_bf16(hA, wh[kt], a0, 0, 0, 0);
      a1 = __builtin_amdgcn_mfma_f32_16x16x32_bf16(hB, wh[kt], a1, 0, 0, 0);
    }

    // ---- E. gate exchange ----
#pragma unroll
    for (int r = 0; r < 4; ++r) {
      sm.gates[wv][0][oct * 4 + r][col] = a0[r];
      sm.gates[wv][1][oct * 4 + r][col] = a1[r];
    }
    __syncthreads();

    // ---- F. epilogue: each wave owns 8 rows (2 cells/lane) ----
    float hn_sv[2];
#pragma unroll
    for (int c2 = 0; c2 < 2; ++c2) {
      int wr = wv * 8 + c2 * 4 + oct;
      int mt = wr >> 4, rr = wr & 15;
      int bg = mpair * 32 + wr;
      int trm = term[t * B_DIM + bg];
      float vi = sm.gates[0][mt][rr][col] + b4[0];
      float vf = sm.gates[1][mt][rr][col] + b4[1];
      float vg = sm.gates[2][mt][rr][col] + b4[2];
      float vo = sm.gates[3][mt][rr][col] + b4[3];
      float cp = trm ? 0.f : c_reg[c2];
      float cn = sigm(vf) * cp + sigm(vi) * tanh_(vg);
      float hn = sigm(vo) * tanh_(cn);
      c_reg[c2] = cn;
      hn_sv[c2] = hn;
      sm.hout[wr][col] = f2bf(hn);
    }
    __syncthreads();

    // ---- G. publish h_{t+1} tile (sc1) + flag; then deferred HBM stores ----
    if (t < T_DIM - 1 && wv == 0) {
      int r = lane >> 1, hh = lane & 1;
      union { u64 q[2]; u32x4 v; } u;
      u.v = *reinterpret_cast<const u32x4*>(&sm.hout[r][hh * 8]);
      unsigned short* dst = ring + (size_t)(t + 1) * 131072 +
                            (size_t)(mpair * 32 + r) * F_DIM + fg * 16 + hh * 8;
      u64* d64 = reinterpret_cast<u64*>(dst);
      __hip_atomic_store(d64,     u.q[0], __ATOMIC_RELAXED, __HIP_MEMORY_SCOPE_AGENT);
      __hip_atomic_store(d64 + 1, u.q[1], __ATOMIC_RELAXED, __HIP_MEMORY_SCOPE_AGENT);
      asm volatile("s_waitcnt vmcnt(0)" ::: "memory");
      if (lane == 0)
        __hip_atomic_store(flags + blockIdx.x, (unsigned int)(t + 1),
                           __ATOMIC_RELAXED, __HIP_MEMORY_SCOPE_AGENT);
    }

#pragma unroll
    for (int c2 = 0; c2 < 2; ++c2) {
      int wr = wv * 8 + c2 * 4 + oct;
      int bg = mpair * 32 + wr;
      out[((size_t)t * B_DIM + bg) * F_DIM + fi] = hn_sv[c2];
      if (t == T_DIM - 1) {
        fc[(size_t)bg * F_DIM + fi] = c_reg[c2];
        fh[(size_t)bg * F_DIM + fi] = hn_sv[c2];
      }
    }
  }
}

extern "C" void kernel_launch(void* const* d_in, const int* in_sizes, int n_in,
                              void* d_out, int out_size, void* d_ws, size_t ws_size,
                              hipStream_t stream) {
  const float* x    = (const float*)d_in[0];
  const int*   term = (const int*)d_in[1];
  const float* c0   = (const float*)d_in[2];
  const float* h0   = (const float*)d_in[3];
  const float* Wi   = (const float*)d_in[4];
  const float* Wh   = (const float*)d_in[5];
  const float* bias = (const float*)d_in[6];
  float* out = (float*)d_out;
  char*  ws  = (char*)d_ws;

  if (ws_size < WS_NEED) return;

  unsigned int*   flags = (unsigned int*)(ws + OFF_FLAGS);
  unsigned short* wip   = (unsigned short*)(ws + OFF_WIP);
  unsigned short* whp   = (unsigned short*)(ws + OFF_WHP);
  unsigned short* ring  = (unsigned short*)(ws + OFF_RING);

  hipMemsetAsync(flags, 0, 4096, stream);
  pack_w<<<dim3(4096), dim3(256), 0, stream>>>(Wi, Wh, wip, whp);
  pack_h<<<dim3(512),  dim3(256), 0, stream>>>(h0, ring);
  lstm_scan<<<dim3(NWGS), dim3(256), 0, stream>>>(x, wip, whp, ring, bias, term, c0, out, flags);
}

// Round 7
// 5283.161 us; speedup vs baseline: 1.3465x; 1.1149x over previous
//
#include <hip/hip_runtime.h>
#include <hip/hip_bf16.h>

#define T_DIM 256
#define B_DIM 128
#define F_DIM 1024
#define G_DIM 4096
#define NWGS  256

typedef short bf8   __attribute__((ext_vector_type(8)));
typedef float f32x4 __attribute__((ext_vector_type(4)));
typedef unsigned int u32x4 __attribute__((ext_vector_type(4)));
typedef unsigned long long u64;

// ---- ws layout (bytes) ----
#define OFF_CTRL  0ull          // grp[8] @ g*128, root @ 1024, epoch @ 2048
#define OFF_WIP   4096ull
#define SZ_WPACK  (8ull*1024*1024)
#define OFF_WHP   (OFF_WIP + SZ_WPACK)
#define OFF_RING  (OFF_WHP + SZ_WPACK)
#define SZ_SLOT   (262144ull)                 // 128*1024 bf16
#define SZ_RING   (256ull * SZ_SLOT)          // 64 MB, write-once per dispatch
#define WS_NEED   (OFF_RING + SZ_RING)

__device__ __forceinline__ unsigned short f2bf(float v) {
  union { float f; unsigned int u; } c; c.f = v;
  unsigned int u = c.u;
  return (unsigned short)((u + 0x7fffu + ((u >> 16) & 1u)) >> 16);  // RNE
}
__device__ __forceinline__ float sigm(float x)  { return 1.f / (1.f + __expf(-x)); }
__device__ __forceinline__ float tanh_(float x) { return 1.f - 2.f / (1.f + __expf(2.f * x)); }
__device__ __forceinline__ bf8 as_bf8(u32x4 v) { union { u32x4 a; bf8 b; } u; u.a = v; return u.b; }

// ---- pack W (fp32 F x 4F) -> MFMA-B frag order bf16: (nt*32+kt)*64+lane ----
__global__ __launch_bounds__(256) void pack_w(const float* __restrict__ Wi,
                                              const float* __restrict__ Wh,
                                              unsigned short* __restrict__ wip,
                                              unsigned short* __restrict__ whp) {
  int gid = blockIdx.x * 256 + threadIdx.x;
  const float* src = (gid >= 524288) ? Wh : Wi;
  unsigned short* dst = (gid >= 524288) ? whp : wip;
  int r  = gid & 524287;
  int nt = r >> 11;
  int kt = (r >> 6) & 31;
  int l  = r & 63;
  int col = nt * 16 + (l & 15);
  int k0  = kt * 32 + ((l >> 4) << 3);
  bf8 v8;
#pragma unroll
  for (int j = 0; j < 8; ++j)
    v8[j] = (short)f2bf(src[(size_t)(k0 + j) * G_DIM + col]);
  *reinterpret_cast<bf8*>(dst + (size_t)r * 8) = v8;
}

// ---- h0 fp32 -> bf16 row-major into ring slot 0 ----
__global__ __launch_bounds__(256) void pack_h(const float* __restrict__ h0,
                                              unsigned short* __restrict__ ring) {
  int i = blockIdx.x * 256 + threadIdx.x;     // 131072
  ring[i] = f2bf(h0[i]);
}

// ---- persistent scan: 256 WGs x 256 thr; wave = gate; Wh in regs ----
__global__ __launch_bounds__(256, 1) void lstm_scan(
    const float* __restrict__ x,                // (T,B,F) fp32
    const unsigned short* __restrict__ wip,
    const unsigned short* __restrict__ whp,
    unsigned short* __restrict__ ring,          // 256 slots, row-major bf16
    const float* __restrict__ bias,
    const int*   __restrict__ term,
    const float* __restrict__ c0,
    float* __restrict__ out,
    unsigned int* __restrict__ ctrl) {

  __shared__ struct {
    u32x4 hst[64][64];               // 64 KB  h A-frags [mt*32+kt][lane]
    u32x4 xst[64][64];               // 64 KB  x A-frags
    float gates[4][2][16][18];       // 9.2 KB
  } sm;

  unsigned int* grp   = ctrl;                    // g*32 dwords apart (128 B)
  unsigned int* root  = ctrl + 256;              // byte 1024
  unsigned int* epoch = ctrl + 512;              // byte 2048

  const int fg    = blockIdx.x & 63;
  const int mpair = blockIdx.x >> 6;             // 0..3 -> rows mpair*32..+32
  const int tid   = threadIdx.x;
  const int wv    = tid >> 6;                    // gate 0..3 (i,f,g,o)
  const int lane  = tid & 63;
  const int col   = lane & 15;
  const int oct   = lane >> 4;                   // k-octet 0..3
  const int fi    = fg * 16 + col;
  const int grpId = blockIdx.x & 7;

  // resident Wh fragments for ntile wv*64+fg (128 VGPRs)
  bf8 wh[32];
  {
    const bf8* whb = reinterpret_cast<const bf8*>(whp) + (size_t)(wv * 64 + fg) * 2048 + lane;
#pragma unroll
    for (int kt = 0; kt < 32; ++kt) wh[kt] = whb[kt * 64];
  }
  const bf8* wib = reinterpret_cast<const bf8*>(wip) + (size_t)(wv * 64 + fg) * 2048 + lane;

  float b4[4];
#pragma unroll
  for (int g = 0; g < 4; ++g) b4[g] = bias[g * F_DIM + fi];

  float c_reg[2];
  {
    int wr0 = wv * 8 + oct;
    c_reg[0] = c0[(size_t)(mpair * 32 + wr0)     * F_DIM + fi];
    c_reg[1] = c0[(size_t)(mpair * 32 + wr0 + 4) * F_DIM + fi];
  }

  const int srow0 = mpair * 32 + col;            // staged batch row, mt=0
  const int srow1 = srow0 + 16;                  // mt=1
  const int fcol0 = oct * 8;

  float* fc = out + (size_t)T_DIM * B_DIM * F_DIM;
  float* fh = fc + (size_t)B_DIM * F_DIM;

#pragma unroll 1
  for (int t = 0; t < T_DIM; ++t) {
    // ---- A. stage x[t] -> LDS bf16 A-frags (overlaps barrier wait) ----
    const float* xt = x + (size_t)t * B_DIM * F_DIM;
#pragma unroll 4
    for (int i = 0; i < 16; ++i) {
      int g2 = wv + 4 * i;
      int kt = g2 & 31;
      int grow = (g2 >> 5) ? srow1 : srow0;
      const float4* s = reinterpret_cast<const float4*>(xt + (size_t)grow * F_DIM + kt * 32 + fcol0);
      float4 v0 = s[0], v1 = s[1];
      union { __hip_bfloat162 h2[4]; u32x4 q; } cv;
      cv.h2[0] = __float22bfloat162_rn(make_float2(v0.x, v0.y));
      cv.h2[1] = __float22bfloat162_rn(make_float2(v0.z, v0.w));
      cv.h2[2] = __float22bfloat162_rn(make_float2(v1.x, v1.y));
      cv.h2[3] = __float22bfloat162_rn(make_float2(v1.z, v1.w));
      sm.xst[g2][lane] = cv.q;
    }

    // ---- B. wait: single-dword epoch broadcast (1 lane per WG) ----
    if (t > 0 && wv == 0) {
      unsigned int e;
      do {
        e = 0;
        if (lane == 0)
          e = __hip_atomic_load(epoch, __ATOMIC_RELAXED, __HIP_MEMORY_SCOPE_AGENT);
        e = (unsigned int)__shfl((int)e, 0, 64);
      } while (e < (unsigned int)t);
      asm volatile("" ::: "memory");
    }
    __syncthreads();   // xst staged + h_t globally visible

    const int trm0 = term[t * B_DIM + srow0];
    const int trm1 = term[t * B_DIM + srow1];
    const unsigned short* hslot = ring + (size_t)t * 131072;

    // ---- C1. issue first 8 h loads (plain cached, coalesced 16B) ----
    u32x4 hq[8];
#pragma unroll
    for (int i = 0; i < 8; ++i) {
      int g2 = wv + 4 * i;
      int kt = g2 & 31;
      int grow = (g2 >> 5) ? srow1 : srow0;
      hq[i] = *reinterpret_cast<const u32x4*>(hslot + (size_t)grow * F_DIM + kt * 32 + fcol0);
    }

    // ---- C2. x @ Wi first half (hides h latency) ----
    f32x4 a0 = {0, 0, 0, 0}, a1 = {0, 0, 0, 0};
#pragma unroll
    for (int kt = 0; kt < 16; ++kt) {
      bf8 wiF = wib[kt * 64];
      a0 = __builtin_amdgcn_mfma_f32_16x16x32_bf16(as_bf8(sm.xst[kt][lane]),      wiF, a0, 0, 0, 0);
      a1 = __builtin_amdgcn_mfma_f32_16x16x32_bf16(as_bf8(sm.xst[32 + kt][lane]), wiF, a1, 0, 0, 0);
    }

    // ---- C3. write first 8 h frags (masked); issue last 8 loads ----
#pragma unroll
    for (int i = 0; i < 8; ++i) {
      int g2 = wv + 4 * i;
      int msk = (g2 >> 5) ? trm1 : trm0;
      u32x4 v = hq[i];
      if (msk) v = (u32x4){0, 0, 0, 0};
      sm.hst[g2][lane] = v;
    }
#pragma unroll
    for (int i = 8; i < 16; ++i) {
      int g2 = wv + 4 * i;
      int kt = g2 & 31;
      int grow = (g2 >> 5) ? srow1 : srow0;
      hq[i - 8] = *reinterpret_cast<const u32x4*>(hslot + (size_t)grow * F_DIM + kt * 32 + fcol0);
    }

    // ---- C4. x @ Wi second half ----
#pragma unroll
    for (int kt = 16; kt < 32; ++kt) {
      bf8 wiF = wib[kt * 64];
      a0 = __builtin_amdgcn_mfma_f32_16x16x32_bf16(as_bf8(sm.xst[kt][lane]),      wiF, a0, 0, 0, 0);
      a1 = __builtin_amdgcn_mfma_f32_16x16x32_bf16(as_bf8(sm.xst[32 + kt][lane]), wiF, a1, 0, 0, 0);
    }

    // ---- C5. write last 8 h frags ----
#pragma unroll
    for (int i = 8; i < 16; ++i) {
      int g2 = wv + 4 * i;
      int msk = (g2 >> 5) ? trm1 : trm0;
      u32x4 v = hq[i - 8];
      if (msk) v = (u32x4){0, 0, 0, 0};
      sm.hst[g2][lane] = v;
    }
    __syncthreads();

    // ---- D. h @ Wh (weights in registers) ----
#pragma unroll
    for (int kt = 0; kt < 32; ++kt) {
      a0 = __builtin_amdgcn_mfma_f32_16x16x32_bf16(as_bf8(sm.hst[kt][lane]),      wh[kt], a0, 0, 0, 0);
      a1 = __builtin_amdgcn_mfma_f32_16x16x32_bf16(as_bf8(sm.hst[32 + kt][lane]), wh[kt], a1, 0, 0, 0);
    }

    // ---- E. gate exchange ----
#pragma unroll
    for (int r = 0; r < 4; ++r) {
      sm.gates[wv][0][oct * 4 + r][col] = a0[r];
      sm.gates[wv][1][oct * 4 + r][col] = a1[r];
    }
    __syncthreads();

    // ---- F. epilogue: each wave owns 8 rows (2 cells/lane) ----
    float hn_sv[2];
#pragma unroll
    for (int c2 = 0; c2 < 2; ++c2) {
      int wr = wv * 8 + c2 * 4 + oct;
      int mt = wr >> 4, rr = wr & 15;
      int bg = mpair * 32 + wr;
      int trm = term[t * B_DIM + bg];
      float vi = sm.gates[0][mt][rr][col] + b4[0];
      float vf = sm.gates[1][mt][rr][col] + b4[1];
      float vg = sm.gates[2][mt][rr][col] + b4[2];
      float vo = sm.gates[3][mt][rr][col] + b4[3];
      float cp = trm ? 0.f : c_reg[c2];
      float cn = sigm(vf) * cp + sigm(vi) * tanh_(vg);
      float hn = sigm(vo) * tanh_(cn);
      c_reg[c2] = cn;
      hn_sv[c2] = hn;
    }

    // ---- G. publish h_{t+1}: each wave stores its own 8 rows (sc1) ----
    if (t < T_DIM - 1) {
      unsigned short* hnext = ring + (size_t)(t + 1) * 131072;
#pragma unroll
      for (int c2 = 0; c2 < 2; ++c2) {
        unsigned int my = f2bf(hn_sv[c2]);
        unsigned int nb = (unsigned int)__shfl_xor((int)my, 1, 64);
        if (!(col & 1)) {
          int row = mpair * 32 + wv * 8 + c2 * 4 + oct;
          unsigned int pk = my | (nb << 16);
          __hip_atomic_store(reinterpret_cast<unsigned int*>(hnext + (size_t)row * F_DIM + (fi & ~1)),
                             pk, __ATOMIC_RELAXED, __HIP_MEMORY_SCOPE_AGENT);
        }
      }
    }
    __syncthreads();   // drains all waves' h stores (vmcnt 0 before s_barrier)

    // ---- H. arrival: hierarchical, 1 RMW per WG ----
    if (wv == 0 && lane == 0) {
      unsigned int old = __hip_atomic_fetch_add(grp + grpId * 32, 1u,
                                                __ATOMIC_RELAXED, __HIP_MEMORY_SCOPE_AGENT);
      if ((old & 31) == 31) {
        unsigned int r = __hip_atomic_fetch_add(root, 1u,
                                                __ATOMIC_RELAXED, __HIP_MEMORY_SCOPE_AGENT);
        if ((r & 7) == 7)
          __hip_atomic_store(epoch, (unsigned int)(t + 1),
                             __ATOMIC_RELAXED, __HIP_MEMORY_SCOPE_AGENT);
      }
    }

    // ---- I. deferred HBM stores (off critical path) ----
#pragma unroll
    for (int c2 = 0; c2 < 2; ++c2) {
      int wr = wv * 8 + c2 * 4 + oct;
      int bg = mpair * 32 + wr;
      out[((size_t)t * B_DIM + bg) * F_DIM + fi] = hn_sv[c2];
      if (t == T_DIM - 1) {
        fc[(size_t)bg * F_DIM + fi] = c_reg[c2];
        fh[(size_t)bg * F_DIM + fi] = hn_sv[c2];
      }
    }
  }
}

extern "C" void kernel_launch(void* const* d_in, const int* in_sizes, int n_in,
                              void* d_out, int out_size, void* d_ws, size_t ws_size,
                              hipStream_t stream) {
  const float* x    = (const float*)d_in[0];
  const int*   term = (const int*)d_in[1];
  const float* c0   = (const float*)d_in[2];
  const float* h0   = (const float*)d_in[3];
  const float* Wi   = (const float*)d_in[4];
  const float* Wh   = (const float*)d_in[5];
  const float* bias = (const float*)d_in[6];
  float* out = (float*)d_out;
  char*  ws  = (char*)d_ws;

  if (ws_size < WS_NEED) return;

  unsigned int*   ctrl = (unsigned int*)(ws + OFF_CTRL);
  unsigned short* wip  = (unsigned short*)(ws + OFF_WIP);
  unsigned short* whp  = (unsigned short*)(ws + OFF_WHP);
  unsigned short* ring = (unsigned short*)(ws + OFF_RING);

  hipMemsetAsync(ctrl, 0, 4096, stream);
  pack_w<<<dim3(4096), dim3(256), 0, stream>>>(Wi, Wh, wip, whp);
  pack_h<<<dim3(512),  dim3(256), 0, stream>>>(h0, ring);
  lstm_scan<<<dim3(NWGS), dim3(256), 0, stream>>>(x, wip, whp, ring, bias, term, c0, out, ctrl);
}